// Round 7
// baseline (596.239 us; speedup 1.0000x reference)
//
#include <hip/hip_runtime.h>
#include <hip/hip_bf16.h>
#include <stdint.h>
#include <stddef.h>

#define NODES 100000
#define EDGES 1600000
#define NCHUNK 6250     // EDGES / 256
#define EDGE_GRID 1250  // 5 chunks per block, exact
#define CPB 5           // chunks per block
#define NTILES 6250     // NODES / 16

typedef float f4 __attribute__((ext_vector_type(4)));
typedef float f32x4 __attribute__((ext_vector_type(4)));
typedef short s8v __attribute__((ext_vector_type(8)));     // bf16x8 MFMA frag
typedef unsigned short u16x8 __attribute__((ext_vector_type(8)));

__device__ __forceinline__ float bf2f(unsigned short u) {
  union { unsigned int i; float f; } v; v.i = ((unsigned int)u) << 16; return v.f;
}
__device__ __forceinline__ unsigned short f2bf(float f) {  // RNE (setup/stores)
  union { float f; unsigned int i; } v; v.f = f;
  return (unsigned short)((v.i + 0x7FFFu + ((v.i >> 16) & 1u)) >> 16);
}
__device__ __forceinline__ short f2bf_hw(float x) {        // hot path: HW cvt
  __hip_bfloat16 h = __float2bfloat16(x);
  union { __hip_bfloat16 h; short s; } u; u.h = h; return u.s;
}

// PQ column permutation: jj = kt<<5 | h<<4 | g<<2 | jp  ->  off = kt<<5 | g<<3 | h<<2 | jp
__device__ __forceinline__ int pqperm(int jj) {
  return (jj & 0x60) | ((jj & 0x0C) << 1) | ((jj & 0x10) >> 2) | (jj & 3);
}

// ---------------------------------------------------------------------------
// Kernel 1 (MFMA): PQ[n][perm(jj)]     = z[n] @ W1[0:64,jj]  + b1[jj]
//                  PQ[n][128+perm(jj)] = z[n] @ W1[64:128,jj]
// z and W1 split hi/lo bf16, 3-term MFMA products => f32-grade precision.
// ---------------------------------------------------------------------------
__global__ __launch_bounds__(256) void node_pq_mfma(
    const float* __restrict__ z, const float* __restrict__ W1,
    const float* __restrict__ b1, unsigned short* __restrict__ PQ) {
  const int t = threadIdx.x;
  const int lane = t & 63;
  const int w = t >> 6;
  const int r = lane & 15, g = lane >> 4;
  const int tile = blockIdx.x * 4 + w;
  if (tile >= NTILES) return;
  const int n0 = tile * 16;

  s8v a_hi[2], a_lo[2];
#pragma unroll
  for (int kt = 0; kt < 2; ++kt) {
    const f4* zp = (const f4*)(z + (size_t)(n0 + r) * 64 + 32 * kt + 8 * g);
    f4 z0 = zp[0], z1 = zp[1];
    float zv[8] = {z0[0], z0[1], z0[2], z0[3], z1[0], z1[1], z1[2], z1[3]};
    s8v hi, lo;
#pragma unroll
    for (int jx = 0; jx < 8; ++jx) {
      short h = f2bf_hw(zv[jx]);
      hi[jx] = h;
      lo[jx] = f2bf_hw(zv[jx] - bf2f((unsigned short)h));
    }
    a_hi[kt] = hi; a_lo[kt] = lo;
  }

#pragma unroll 1
  for (int nt = 0; nt < 16; ++nt) {
    const int col = (nt & 7) * 16 + r;
    const int rowbase = (nt < 8) ? 0 : 64;
    const float init = (nt < 8) ? b1[col] : 0.f;
    f32x4 acc = {init, init, init, init};
#pragma unroll
    for (int kt = 0; kt < 2; ++kt) {
      s8v whi, wlo;
#pragma unroll
      for (int jx = 0; jx < 8; ++jx) {
        float wv = W1[(size_t)(rowbase + 32 * kt + 8 * g + jx) * 128 + col];
        short h = f2bf_hw(wv);
        whi[jx] = h;
        wlo[jx] = f2bf_hw(wv - bf2f((unsigned short)h));
      }
      acc = __builtin_amdgcn_mfma_f32_16x16x32_bf16(a_hi[kt], whi, acc, 0, 0, 0);
      acc = __builtin_amdgcn_mfma_f32_16x16x32_bf16(a_lo[kt], whi, acc, 0, 0, 0);
      acc = __builtin_amdgcn_mfma_f32_16x16x32_bf16(a_hi[kt], wlo, acc, 0, 0, 0);
    }
    const int outcol = (nt < 8) ? pqperm(col) : (128 + pqperm(col));
#pragma unroll
    for (int reg = 0; reg < 4; ++reg)
      PQ[(size_t)(n0 + 4 * g + reg) * 256 + outcol] = f2bf(acc[reg]);
  }
}

// ---------------------------------------------------------------------------
// Kernel 2: MFMA edge kernel with cross-chunk software pipelining:
// next chunk's eidx/eattr issued at top of current compute; next chunk's st0
// PQ loads issued before COMPUTE(3). 5 chunks per block.
// ---------------------------------------------------------------------------
__global__ __launch_bounds__(256, 4) void edge_mfma_kernel(
    const int* __restrict__ eidx, const float* __restrict__ eattr,
    const float* __restrict__ W1, const float* __restrict__ W2,
    const float* __restrict__ b2, const float* __restrict__ W3,
    const float* __restrict__ b3,
    const unsigned short* __restrict__ PQ, float* __restrict__ out) {
  const int t = threadIdx.x;
  const int lane = t & 63;
  const int w = t >> 6;
  const int r = lane & 15;   // edge row (A side) / col (C side)
  const int g = lane >> 4;   // k-group

  // Persistent W2 B-frags: jj(kt,g,jx) = 32kt + 16(jx>>2) + 4g + (jx&3)
  s8v bfrag[4][4];
#pragma unroll
  for (int kt = 0; kt < 4; ++kt)
#pragma unroll
    for (int nt = 0; nt < 4; ++nt) {
      s8v f;
#pragma unroll
      for (int jx = 0; jx < 8; ++jx) {
        int h = jx >> 2, jp = jx & 3;
        int jjv = 32 * kt + 16 * h + 4 * g + jp;
        f[jx] = (short)f2bf(W2[(size_t)jjv * 64 + nt * 16 + r]);
      }
      bfrag[kt][nt] = f;
    }
  // W1c A-frags for the E-mfma (k-slot = 8g+jx; nonzero only g==0).
  s8v w1cf[8];
#pragma unroll
  for (int mt = 0; mt < 8; ++mt) {
    s8v f = {0, 0, 0, 0, 0, 0, 0, 0};
    if (g == 0) {
#pragma unroll
      for (int jx = 0; jx < 8; ++jx)
        f[jx] = (short)f2bf(W1[(size_t)(128 + jx) * 128 + 16 * mt + r]);
    }
    w1cf[mt] = f;
  }
  float b2v[4], w3v[4];
#pragma unroll
  for (int nt = 0; nt < 4; ++nt) { b2v[nt] = b2[nt * 16 + r]; w3v[nt] = W3[nt * 16 + r]; }
  const float bias3 = b3[0];
  const f32x4 zc = {0.f, 0.f, 0.f, 0.f};

  int srcv[4], dstv[4];
  s8v eafv[4];
  u16x8 p[4][4], q[4][4];

#define PACK_EA(pk, a0, a1)                                                    \
    {                                                                          \
      pk[0] = (unsigned int)(unsigned short)f2bf_hw(a0[0]) |                   \
              ((unsigned int)(unsigned short)f2bf_hw(a0[1]) << 16);            \
      pk[1] = (unsigned int)(unsigned short)f2bf_hw(a0[2]) |                   \
              ((unsigned int)(unsigned short)f2bf_hw(a0[3]) << 16);            \
      pk[2] = (unsigned int)(unsigned short)f2bf_hw(a1[0]) |                   \
              ((unsigned int)(unsigned short)f2bf_hw(a1[1]) << 16);            \
      pk[3] = (unsigned int)(unsigned short)f2bf_hw(a1[2]) |                   \
              ((unsigned int)(unsigned short)f2bf_hw(a1[3]) << 16);            \
    }

#define PQ_LOAD(s)                                                             \
    {                                                                          \
      const unsigned short* Pb = PQ + (size_t)srcv[s] * 256 + 8 * g;           \
      const unsigned short* Qb = PQ + (size_t)dstv[s] * 256 + 128 + 8 * g;     \
      _Pragma("unroll")                                                        \
      for (int kt = 0; kt < 4; ++kt) {                                         \
        p[s][kt] = *(const u16x8*)(Pb + 32 * kt);                              \
        q[s][kt] = *(const u16x8*)(Qb + 32 * kt);                              \
      }                                                                        \
    }

#define PQ_COMPUTE(s, EB)                                                      \
    {                                                                          \
      const int e0 = (EB) + (s) * 16;                                          \
      f32x4 acc[4] = {zc, zc, zc, zc};                                         \
      _Pragma("unroll")                                                        \
      for (int kt = 0; kt < 4; ++kt) {                                         \
        f32x4 E0 = __builtin_amdgcn_mfma_f32_16x16x32_bf16(w1cf[2 * kt], eafv[s], zc, 0, 0, 0); \
        f32x4 E1 = __builtin_amdgcn_mfma_f32_16x16x32_bf16(w1cf[2 * kt + 1], eafv[s], zc, 0, 0, 0); \
        s8v af;                                                                \
        _Pragma("unroll")                                                      \
        for (int jp = 0; jp < 4; ++jp) {                                       \
          float s0 = bf2f(p[s][kt][jp]) + bf2f(q[s][kt][jp]) + E0[jp];         \
          af[jp] = f2bf_hw(fmaxf(s0, 0.f));                                    \
          float s1 = bf2f(p[s][kt][4 + jp]) + bf2f(q[s][kt][4 + jp]) + E1[jp]; \
          af[4 + jp] = f2bf_hw(fmaxf(s1, 0.f));                                \
        }                                                                      \
        _Pragma("unroll")                                                      \
        for (int nt = 0; nt < 4; ++nt)                                         \
          acc[nt] = __builtin_amdgcn_mfma_f32_16x16x32_bf16(af, bfrag[kt][nt], acc[nt], 0, 0, 0); \
      }                                                                        \
      float pr0 = 0.f, pr1 = 0.f, pr2 = 0.f, pr3 = 0.f;                        \
      _Pragma("unroll")                                                        \
      for (int nt = 0; nt < 4; ++nt) {                                         \
        pr0 = fmaf(fmaxf(acc[nt][0] + b2v[nt], 0.f), w3v[nt], pr0);            \
        pr1 = fmaf(fmaxf(acc[nt][1] + b2v[nt], 0.f), w3v[nt], pr1);            \
        pr2 = fmaf(fmaxf(acc[nt][2] + b2v[nt], 0.f), w3v[nt], pr2);            \
        pr3 = fmaf(fmaxf(acc[nt][3] + b2v[nt], 0.f), w3v[nt], pr3);            \
      }                                                                        \
      _Pragma("unroll")                                                        \
      for (int m = 1; m < 16; m <<= 1) {                                       \
        pr0 += __shfl_xor(pr0, m, 64);                                         \
        pr1 += __shfl_xor(pr1, m, 64);                                         \
        pr2 += __shfl_xor(pr2, m, 64);                                         \
        pr3 += __shfl_xor(pr3, m, 64);                                         \
      }                                                                        \
      if (r < 4) {                                                             \
        float v = (r == 0) ? pr0 : (r == 1) ? pr1 : (r == 2) ? pr2 : pr3;      \
        out[e0 + 4 * g + r] = v + bias3;                                       \
      }                                                                        \
    }

  // ---- prologue: chunk 0 of this block ----
  {
    const int ebase0 = blockIdx.x * 256 + w * 64;
    const int s_all = eidx[ebase0 + lane];
    const int d_all = eidx[EDGES + ebase0 + lane];
    const f4* eap = (const f4*)(eattr + (size_t)(ebase0 + lane) * 8);
    f4 a0 = eap[0], a1 = eap[1];
    unsigned int pk[4];
    PACK_EA(pk, a0, a1)
#pragma unroll
    for (int st = 0; st < 4; ++st) {
      const int idx = st * 16 + r;
      srcv[st] = __shfl(s_all, idx, 64);
      dstv[st] = __shfl(d_all, idx, 64);
      union { unsigned int u[4]; s8v v; } eu;
#pragma unroll
      for (int c = 0; c < 4; ++c) eu.u[c] = (unsigned int)__shfl((int)pk[c], idx, 64);
      eafv[st] = eu.v;
    }
    PQ_LOAD(0)
  }

#pragma unroll 1
  for (int it = 0; it < CPB; ++it) {
    const int ebase = (blockIdx.x + it * EDGE_GRID) * 256 + w * 64;
    const int nbase = ebase + EDGE_GRID * 256;
    // issue next chunk's raw loads early (overlap all of this chunk's compute)
    int nsrc = 0, ndst = 0;
    f4 na0 = {0.f, 0.f, 0.f, 0.f}, na1 = {0.f, 0.f, 0.f, 0.f};
    if (it < CPB - 1) {
      nsrc = eidx[nbase + lane];
      ndst = eidx[EDGES + nbase + lane];
      const f4* neap = (const f4*)(eattr + (size_t)(nbase + lane) * 8);
      na0 = neap[0]; na1 = neap[1];
    }
    PQ_LOAD(1)
    PQ_COMPUTE(0, ebase)
    PQ_LOAD(2)
    PQ_COMPUTE(1, ebase)
    PQ_LOAD(3)
    PQ_COMPUTE(2, ebase)
    s8v tmp3 = eafv[3];
    if (it < CPB - 1) {
      unsigned int npk[4];
      PACK_EA(npk, na0, na1)
#pragma unroll
      for (int st = 0; st < 4; ++st) {
        const int idx = st * 16 + r;
        srcv[st] = __shfl(nsrc, idx, 64);
        dstv[st] = __shfl(ndst, idx, 64);
        union { unsigned int u[4]; s8v v; } eu;
#pragma unroll
        for (int c = 0; c < 4; ++c) eu.u[c] = (unsigned int)__shfl((int)npk[c], idx, 64);
        if (st == 3) { s8v sw = eafv[3]; eafv[3] = eu.v; tmp3 = sw; }
        else eafv[st] = eu.v;
      }
      // swap so COMPUTE(3) uses the CURRENT chunk's eaf: eafv[3] holds next's,
      // tmp3 holds cur's -> exchange roles below
      { s8v cur = tmp3; tmp3 = eafv[3]; eafv[3] = cur; }
      PQ_LOAD(0)  // next chunk st0 (p[0]/q[0] free since COMPUTE(0) done)
    }
    PQ_COMPUTE(3, ebase)
    if (it < CPB - 1) eafv[3] = tmp3;  // commit next chunk's eaf[3]
  }
#undef PQ_LOAD
#undef PQ_COMPUTE
#undef PACK_EA
}

extern "C" void kernel_launch(void* const* d_in, const int* in_sizes, int n_in,
                              void* d_out, int out_size, void* d_ws, size_t ws_size,
                              hipStream_t stream) {
  const float* z     = (const float*)d_in[0];
  const int*   eidx  = (const int*)d_in[1];
  const float* eattr = (const float*)d_in[2];
  const float* W1    = (const float*)d_in[3];
  const float* b1    = (const float*)d_in[4];
  const float* W2    = (const float*)d_in[5];
  const float* b2    = (const float*)d_in[6];
  const float* W3    = (const float*)d_in[7];
  const float* b3    = (const float*)d_in[8];
  float* out = (float*)d_out;

  unsigned short* PQ = (unsigned short*)d_ws;  // 51.2 MB
  node_pq_mfma<<<(NTILES + 3) / 4, 256, 0, stream>>>(z, W1, b1, PQ);
  edge_mfma_kernel<<<EDGE_GRID, 256, 0, stream>>>(
      eidx, eattr, W1, W2, b2, W3, b3, PQ, out);
}

// Round 11
// 173.300 us; speedup vs baseline: 3.4405x; 3.4405x over previous
//
#include <hip/hip_runtime.h>
#include <hip/hip_bf16.h>
#include <stdint.h>
#include <stddef.h>

#define NODES 100000
#define EDGES 1600000
#define NCHUNK 6250     // EDGES / 256
#define EDGE_GRID 1250  // 5 chunks per block (chunk-stride), round-4 proven
#define NTILES 6250     // NODES / 16

typedef float f4 __attribute__((ext_vector_type(4)));
typedef float f32x4 __attribute__((ext_vector_type(4)));
typedef short s8v __attribute__((ext_vector_type(8)));     // bf16x8 MFMA frag
typedef unsigned short u16x8 __attribute__((ext_vector_type(8)));

__device__ __forceinline__ float bf2f(unsigned short u) {
  union { unsigned int i; float f; } v; v.i = ((unsigned int)u) << 16; return v.f;
}
__device__ __forceinline__ unsigned short f2bf(float f) {  // RNE (setup/stores)
  union { float f; unsigned int i; } v; v.f = f;
  return (unsigned short)((v.i + 0x7FFFu + ((v.i >> 16) & 1u)) >> 16);
}
__device__ __forceinline__ short f2bf_hw(float x) {        // hot path: HW cvt
  __hip_bfloat16 h = __float2bfloat16(x);
  union { __hip_bfloat16 h; short s; } u; u.h = h; return u.s;
}

// PQ column permutation: jj = kt<<5 | h<<4 | g<<2 | jp  ->  off = kt<<5 | g<<3 | h<<2 | jp
__device__ __forceinline__ int pqperm(int jj) {
  return (jj & 0x60) | ((jj & 0x0C) << 1) | ((jj & 0x10) >> 2) | (jj & 3);
}

// ---------------------------------------------------------------------------
// Kernel 1 (MFMA, round-6 verbatim): PQ[n][perm(jj)]     = z[n]@W1[0:64,jj] + b1[jj]
//                                    PQ[n][128+perm(jj)] = z[n]@W1[64:128,jj]
// z and W1 split hi/lo bf16, 3-term MFMA products => f32-grade precision.
// ---------------------------------------------------------------------------
__global__ __launch_bounds__(256) void node_pq_mfma(
    const float* __restrict__ z, const float* __restrict__ W1,
    const float* __restrict__ b1, unsigned short* __restrict__ PQ) {
  const int t = threadIdx.x;
  const int lane = t & 63;
  const int w = t >> 6;
  const int r = lane & 15, g = lane >> 4;
  const int tile = blockIdx.x * 4 + w;
  if (tile >= NTILES) return;
  const int n0 = tile * 16;

  s8v a_hi[2], a_lo[2];
#pragma unroll
  for (int kt = 0; kt < 2; ++kt) {
    const f4* zp = (const f4*)(z + (size_t)(n0 + r) * 64 + 32 * kt + 8 * g);
    f4 z0 = zp[0], z1 = zp[1];
    float zv[8] = {z0[0], z0[1], z0[2], z0[3], z1[0], z1[1], z1[2], z1[3]};
    s8v hi, lo;
#pragma unroll
    for (int jx = 0; jx < 8; ++jx) {
      short h = f2bf_hw(zv[jx]);
      hi[jx] = h;
      lo[jx] = f2bf_hw(zv[jx] - bf2f((unsigned short)h));
    }
    a_hi[kt] = hi; a_lo[kt] = lo;
  }

#pragma unroll 1
  for (int nt = 0; nt < 16; ++nt) {
    const int col = (nt & 7) * 16 + r;
    const int rowbase = (nt < 8) ? 0 : 64;
    const float init = (nt < 8) ? b1[col] : 0.f;
    f32x4 acc = {init, init, init, init};
#pragma unroll
    for (int kt = 0; kt < 2; ++kt) {
      s8v whi, wlo;
#pragma unroll
      for (int jx = 0; jx < 8; ++jx) {
        float wv = W1[(size_t)(rowbase + 32 * kt + 8 * g + jx) * 128 + col];
        short h = f2bf_hw(wv);
        whi[jx] = h;
        wlo[jx] = f2bf_hw(wv - bf2f((unsigned short)h));
      }
      acc = __builtin_amdgcn_mfma_f32_16x16x32_bf16(a_hi[kt], whi, acc, 0, 0, 0);
      acc = __builtin_amdgcn_mfma_f32_16x16x32_bf16(a_lo[kt], whi, acc, 0, 0, 0);
      acc = __builtin_amdgcn_mfma_f32_16x16x32_bf16(a_hi[kt], wlo, acc, 0, 0, 0);
    }
    const int outcol = (nt < 8) ? pqperm(col) : (128 + pqperm(col));
#pragma unroll
    for (int reg = 0; reg < 4; ++reg)
      PQ[(size_t)(n0 + 4 * g + reg) * 256 + outcol] = f2bf(acc[reg]);
  }
}

// ---------------------------------------------------------------------------
// Kernel 2 (round-4 verbatim): MFMA edge kernel, chunk-level coalesced
// index/attr loads + shuffle distribution; st loop fully unrolled so PQ
// gathers of all 4 sub-tiles can overlap (compiler-scheduled depth).
// ---------------------------------------------------------------------------
__global__ __launch_bounds__(256) void edge_mfma_kernel(
    const int* __restrict__ eidx, const float* __restrict__ eattr,
    const float* __restrict__ W1, const float* __restrict__ W2,
    const float* __restrict__ b2, const float* __restrict__ W3,
    const float* __restrict__ b3,
    const unsigned short* __restrict__ PQ, float* __restrict__ out) {
  const int t = threadIdx.x;
  const int lane = t & 63;
  const int w = t >> 6;
  const int r = lane & 15;   // edge row (A side) / col (C side)
  const int g = lane >> 4;   // k-group

  // Persistent W2 B-frags: jj(kt,g,jx) = 32kt + 16(jx>>2) + 4g + (jx&3)
  s8v bfrag[4][4];
#pragma unroll
  for (int kt = 0; kt < 4; ++kt)
#pragma unroll
    for (int nt = 0; nt < 4; ++nt) {
      s8v f;
#pragma unroll
      for (int jx = 0; jx < 8; ++jx) {
        int h = jx >> 2, jp = jx & 3;
        int jjv = 32 * kt + 16 * h + 4 * g + jp;
        f[jx] = (short)f2bf(W2[(size_t)jjv * 64 + nt * 16 + r]);
      }
      bfrag[kt][nt] = f;
    }
  // W1c A-frags for the E-mfma (k-slot = 8g+jx; nonzero only g==0).
  s8v w1cf[8];
#pragma unroll
  for (int mt = 0; mt < 8; ++mt) {
    s8v f = {0, 0, 0, 0, 0, 0, 0, 0};
    if (g == 0) {
#pragma unroll
      for (int jx = 0; jx < 8; ++jx)
        f[jx] = (short)f2bf(W1[(size_t)(128 + jx) * 128 + 16 * mt + r]);
    }
    w1cf[mt] = f;
  }
  float b2v[4], w3v[4];
#pragma unroll
  for (int nt = 0; nt < 4; ++nt) { b2v[nt] = b2[nt * 16 + r]; w3v[nt] = W3[nt * 16 + r]; }
  const float bias3 = b3[0];
  const f32x4 zc = {0.f, 0.f, 0.f, 0.f};

#pragma unroll 1
  for (int chunk = blockIdx.x; chunk < NCHUNK; chunk += EDGE_GRID) {
    const int ebase = chunk * 256 + w * 64;
    // Chunk-level coalesced loads: this wave's 64 edges.
    const int src_all = eidx[ebase + lane];
    const int dst_all = eidx[EDGES + ebase + lane];
    unsigned int ea_pk[4];
    {
      const f4* eap = (const f4*)(eattr + (size_t)(ebase + lane) * 8);
      f4 a0 = eap[0], a1 = eap[1];
      ea_pk[0] = (unsigned int)(unsigned short)f2bf_hw(a0[0]) |
                 ((unsigned int)(unsigned short)f2bf_hw(a0[1]) << 16);
      ea_pk[1] = (unsigned int)(unsigned short)f2bf_hw(a0[2]) |
                 ((unsigned int)(unsigned short)f2bf_hw(a0[3]) << 16);
      ea_pk[2] = (unsigned int)(unsigned short)f2bf_hw(a1[0]) |
                 ((unsigned int)(unsigned short)f2bf_hw(a1[1]) << 16);
      ea_pk[3] = (unsigned int)(unsigned short)f2bf_hw(a1[2]) |
                 ((unsigned int)(unsigned short)f2bf_hw(a1[3]) << 16);
    }

#pragma unroll
    for (int st = 0; st < 4; ++st) {
      const int e0 = ebase + st * 16;
      const int idx = st * 16 + r;
      const int srcv = __shfl(src_all, idx, 64);
      const int dstv = __shfl(dst_all, idx, 64);
      // eaf via shuffle of packed attrs (g!=0 lanes harmless: A is zero there)
      s8v eaf;
#pragma unroll
      for (int c = 0; c < 4; ++c) {
        unsigned int pk = (unsigned int)__shfl((int)ea_pk[c], idx, 64);
        eaf[2 * c] = (short)(pk & 0xFFFFu);
        eaf[2 * c + 1] = (short)(pk >> 16);
      }
      const unsigned short* Pb = PQ + (size_t)srcv * 256 + 8 * g;
      const unsigned short* Qb = PQ + (size_t)dstv * 256 + 128 + 8 * g;
      u16x8 p[4], q[4];
#pragma unroll
      for (int kt = 0; kt < 4; ++kt) {
        p[kt] = *(const u16x8*)(Pb + 32 * kt);
        q[kt] = *(const u16x8*)(Qb + 32 * kt);
      }
      f32x4 acc[4] = {zc, zc, zc, zc};
#pragma unroll
      for (int kt = 0; kt < 4; ++kt) {
        f32x4 E0 = __builtin_amdgcn_mfma_f32_16x16x32_bf16(w1cf[2 * kt], eaf, zc, 0, 0, 0);
        f32x4 E1 = __builtin_amdgcn_mfma_f32_16x16x32_bf16(w1cf[2 * kt + 1], eaf, zc, 0, 0, 0);
        s8v af;
#pragma unroll
        for (int jp = 0; jp < 4; ++jp) {
          float s0 = bf2f(p[kt][jp]) + bf2f(q[kt][jp]) + E0[jp];
          af[jp] = f2bf_hw(fmaxf(s0, 0.f));
          float s1 = bf2f(p[kt][4 + jp]) + bf2f(q[kt][4 + jp]) + E1[jp];
          af[4 + jp] = f2bf_hw(fmaxf(s1, 0.f));
        }
#pragma unroll
        for (int nt = 0; nt < 4; ++nt)
          acc[nt] = __builtin_amdgcn_mfma_f32_16x16x32_bf16(af, bfrag[kt][nt], acc[nt], 0, 0, 0);
      }
      // Layer 3 + 16-lane butterfly
      float pr0 = 0.f, pr1 = 0.f, pr2 = 0.f, pr3 = 0.f;
#pragma unroll
      for (int nt = 0; nt < 4; ++nt) {
        pr0 = fmaf(fmaxf(acc[nt][0] + b2v[nt], 0.f), w3v[nt], pr0);
        pr1 = fmaf(fmaxf(acc[nt][1] + b2v[nt], 0.f), w3v[nt], pr1);
        pr2 = fmaf(fmaxf(acc[nt][2] + b2v[nt], 0.f), w3v[nt], pr2);
        pr3 = fmaf(fmaxf(acc[nt][3] + b2v[nt], 0.f), w3v[nt], pr3);
      }
#pragma unroll
      for (int m = 1; m < 16; m <<= 1) {
        pr0 += __shfl_xor(pr0, m, 64);
        pr1 += __shfl_xor(pr1, m, 64);
        pr2 += __shfl_xor(pr2, m, 64);
        pr3 += __shfl_xor(pr3, m, 64);
      }
      if (r < 4) {
        float v = (r == 0) ? pr0 : (r == 1) ? pr1 : (r == 2) ? pr2 : pr3;
        out[e0 + 4 * g + r] = v + bias3;
      }
    }
  }
}

extern "C" void kernel_launch(void* const* d_in, const int* in_sizes, int n_in,
                              void* d_out, int out_size, void* d_ws, size_t ws_size,
                              hipStream_t stream) {
  const float* z     = (const float*)d_in[0];
  const int*   eidx  = (const int*)d_in[1];
  const float* eattr = (const float*)d_in[2];
  const float* W1    = (const float*)d_in[3];
  const float* b1    = (const float*)d_in[4];
  const float* W2    = (const float*)d_in[5];
  const float* b2    = (const float*)d_in[6];
  const float* W3    = (const float*)d_in[7];
  const float* b3    = (const float*)d_in[8];
  float* out = (float*)d_out;

  unsigned short* PQ = (unsigned short*)d_ws;  // 51.2 MB
  node_pq_mfma<<<(NTILES + 3) / 4, 256, 0, stream>>>(z, W1, b1, PQ);
  edge_mfma_kernel<<<EDGE_GRID, 256, 0, stream>>>(
      eidx, eattr, W1, W2, b2, W3, b3, PQ, out);
}